// Round 18
// baseline (1354.114 us; speedup 1.0000x reference)
//
#include <hip/hip_runtime.h>
#include <cstdint>
#include <cstddef>

#define B_   4
#define V_   50000
#define VP_  50048                       // 782*64  (fb/vf row count)
#define VPT_ 50176                       // 392*128 (specf grid coverage; evb rows)
#define K_   128
#define C_   128
#define NNZ_ 800000
#define HID_ 256

#define NB_   391                        // buckets of 128 rows
#define CAP_  2560                       // per-(d,bucket) capacity
#define CH_   4096                       // entries per binfill block
#define NBF_  196                        // ceil(NNZ_/CH_)

typedef __attribute__((ext_vector_type(8))) short short8;
typedef __attribute__((ext_vector_type(4))) float f32x4;
typedef unsigned short us;

__device__ __forceinline__ us f2b(float f) {
    union { float f; unsigned u; } v; v.f = f;
    unsigned r = v.u + 0x7fffu + ((v.u >> 16) & 1u);
    return (us)(r >> 16);
}
__device__ __forceinline__ float b2f(us h) {
    union { unsigned u; float f; } v; v.u = ((unsigned)h) << 16; return v.f;
}
__device__ __forceinline__ unsigned pk(float lo, float hi) {
    return (unsigned)f2b(lo) | ((unsigned)f2b(hi) << 16);
}

// ============================================================================
// k_cvt_all: W0/W1 bf16 convert + Aw permuted bf16 convert (one dispatch)
// ============================================================================
__global__ __launch_bounds__(256) void k_cvt_all(
    const float* __restrict__ W0, const float* __restrict__ W1,
    const float* __restrict__ Aw,
    us* __restrict__ W0b, us* __restrict__ W1b, us* __restrict__ Awb)
{
    int t = blockIdx.x * 256 + threadIdx.x;          // 163840 threads total
    if (t < 16384) {
        const float* src; us* dst; int i8;
        if (t < 12288) { i8 = t * 8;            src = W0 + i8; dst = W0b + i8; }
        else           { i8 = (t - 12288) * 8;  src = W1 + i8; dst = W1b + i8; }
        float4 x0 = *(const float4*)src;
        float4 x1 = *(const float4*)(src + 4);
        uint4 u;
        u.x = pk(x0.x, x0.y); u.y = pk(x0.z, x0.w);
        u.z = pk(x1.x, x1.y); u.w = pk(x1.z, x1.w);
        *(uint4*)dst = u;
    } else {
        int p  = t - 16384;                          // < 147456
        int p1 = p / 384, p2 = p - p1 * 384;
        int q1 = 3 * (p1 & 127) + (p1 >> 7);
        int q2 = 3 * (p2 & 127) + (p2 >> 7);
        Awb[p] = f2b(Aw[q1 * 384 + q2]);
    }
}

// ============================================================================
// k_specf: FUSED transpose + spectral projection + evb stash (r17 proven)
// ============================================================================
__global__ __launch_bounds__(256) void k_specf(
    const float* __restrict__ x_in, const float* __restrict__ mass,
    const float* __restrict__ evecs,
    float* __restrict__ x_spec, us* __restrict__ fb, us* __restrict__ evb, int b)
{
    const int vb  = blockIdx.x * 128;
    const int tid = threadIdx.x;
    const int w   = tid >> 6;
    const int lr  = tid & 15;
    const int lk  = (tid & 63) >> 4;

    __shared__ us ev_t[128][40];   // [k][v_local], 80B row stride (16B aligned)
    __shared__ us mx_t[128][40];   // [c][v_local]

    f32x4 z = {0.f, 0.f, 0.f, 0.f};
    f32x4 acc[2][8];
#pragma unroll
    for (int mi = 0; mi < 2; ++mi)
#pragma unroll
        for (int ni = 0; ni < 8; ++ni) acc[mi][ni] = z;

    for (int s = 0; s < 4; ++s) {
        int v0 = vb + s * 32;
        __syncthreads();
#pragma unroll
        for (int it = 0; it < 4; ++it) {
            int f   = tid + it * 256;          // 0..1023
            int row = f >> 5;                  // 0..31
            int col = (f & 31) * 4;
            int v   = v0 + row;
            float4 x = make_float4(0.f, 0.f, 0.f, 0.f);
            float4 e = make_float4(0.f, 0.f, 0.f, 0.f);
            float  m = 0.f;
            if (v < V_) {
                x = *(const float4*)&x_in [((size_t)b * V_ + v) * C_ + col];
                e = *(const float4*)&evecs[((size_t)b * V_ + v) * K_ + col];
                m = mass[b * V_ + v];
                uint2 u; u.x = pk(x.x, x.y); u.y = pk(x.z, x.w);
                *(uint2*)&fb[(size_t)v * 384 + col] = u;
            }
            {   // evb row (unconditional: v < VPT_ always; zeros beyond V_)
                uint2 ue; ue.x = pk(e.x, e.y); ue.y = pk(e.z, e.w);
                *(uint2*)&evb[(size_t)v * 128 + col] = ue;
            }
            mx_t[col + 0][row] = f2b(x.x * m); mx_t[col + 1][row] = f2b(x.y * m);
            mx_t[col + 2][row] = f2b(x.z * m); mx_t[col + 3][row] = f2b(x.w * m);
            ev_t[col + 0][row] = f2b(e.x); ev_t[col + 1][row] = f2b(e.y);
            ev_t[col + 2][row] = f2b(e.z); ev_t[col + 3][row] = f2b(e.w);
        }
        __syncthreads();

        short8 a[2], bf8[8];
#pragma unroll
        for (int mi = 0; mi < 2; ++mi)
            a[mi] = *(const short8*)&ev_t[w * 32 + mi * 16 + lr][lk * 8];
#pragma unroll
        for (int ni = 0; ni < 8; ++ni)
            bf8[ni] = *(const short8*)&mx_t[ni * 16 + lr][lk * 8];
#pragma unroll
        for (int mi = 0; mi < 2; ++mi)
#pragma unroll
            for (int ni = 0; ni < 8; ++ni)
                acc[mi][ni] = __builtin_amdgcn_mfma_f32_16x16x32_bf16(
                    a[mi], bf8[ni], acc[mi][ni], 0, 0, 0);
    }
#pragma unroll
    for (int mi = 0; mi < 2; ++mi)
#pragma unroll
        for (int ni = 0; ni < 8; ++ni)
#pragma unroll
            for (int r = 0; r < 4; ++r) {
                int k = w * 32 + mi * 16 + lk * 4 + r;
                int c = ni * 16 + lr;
                atomicAdd(&x_spec[((size_t)b * K_ + k) * C_ + c], acc[mi][ni][r]);
            }
}

// ============================================================================
// k_scale2: spec_t[c][k] = bf16( exp(-evals[b,k]*max(dt[c],1e-8)) * x_spec[b,k,c] )
// ============================================================================
__global__ __launch_bounds__(256) void k_scale2(
    const float* __restrict__ evals, const float* __restrict__ dt,
    const float* __restrict__ x_spec, us* __restrict__ spec_t, int b)
{
    int i = blockIdx.x * 256 + threadIdx.x;    // < 16384
    int c = i >> 7;
    int k = i & 127;
    float t = fmaxf(dt[c], 1e-8f);
    float v = __expf(-evals[b * K_ + k] * t) * x_spec[((size_t)b * K_ + k) * C_ + c];
    spec_t[i] = f2b(v);
}

// ============================================================================
// k_frombasis_mfma: fb[v][128+c] = bf16( sum_k evb[v][k] * spec_t[c][k] )
// ============================================================================
__global__ __launch_bounds__(256) void k_frombasis_mfma(
    const us* __restrict__ evb, const us* __restrict__ spec_t,
    us* __restrict__ fb, int b)
{
    const int v0  = blockIdx.x * 64;
    const int tid = threadIdx.x;
    const int w   = tid >> 6;
    const int lr  = tid & 15;
    const int lk  = (tid & 63) >> 4;

    f32x4 z = {0.f, 0.f, 0.f, 0.f};
    f32x4 acc[4][2];
#pragma unroll
    for (int mi = 0; mi < 4; ++mi)
#pragma unroll
        for (int ni = 0; ni < 2; ++ni) acc[mi][ni] = z;

#pragma unroll
    for (int ks = 0; ks < 4; ++ks) {
        int ko = ks * 32 + lk * 8;
        short8 a[4], bf[2];
#pragma unroll
        for (int mi = 0; mi < 4; ++mi)
            a[mi] = *(const short8*)&evb[(size_t)(v0 + mi * 16 + lr) * 128 + ko];
#pragma unroll
        for (int ni = 0; ni < 2; ++ni)
            bf[ni] = *(const short8*)&spec_t[(size_t)(w * 32 + ni * 16 + lr) * K_ + ko];
#pragma unroll
        for (int mi = 0; mi < 4; ++mi)
#pragma unroll
            for (int ni = 0; ni < 2; ++ni)
                acc[mi][ni] = __builtin_amdgcn_mfma_f32_16x16x32_bf16(
                    a[mi], bf[ni], acc[mi][ni], 0, 0, 0);
    }
#pragma unroll
    for (int mi = 0; mi < 4; ++mi)
#pragma unroll
        for (int ni = 0; ni < 2; ++ni)
#pragma unroll
            for (int r = 0; r < 4; ++r) {
                int v = v0 + mi * 16 + lk * 4 + r;
                int c = w * 32 + ni * 16 + lr;
                if (v < V_) fb[(size_t)v * 384 + 128 + c] = f2b(acc[mi][ni][r]);
            }
}

// ============================================================================
// k_binfill: LDS-binned bucket scatter (proven). Entry: {val, (q<<23)|(rlow<<16)|col}
// ============================================================================
__global__ __launch_bounds__(256) void k_binfill(
    const int* __restrict__ r0, const int* __restrict__ r1, const int* __restrict__ r2,
    const int* __restrict__ c0, const int* __restrict__ c1, const int* __restrict__ c2,
    const float* __restrict__ v0, const float* __restrict__ v1, const float* __restrict__ v2,
    uint2* __restrict__ chunk, int* __restrict__ gcnt, int b)
{
    const int d   = blockIdx.y;
    const int e0  = blockIdx.x * CH_;
    const int tid = threadIdx.x;
    const int*   rr = (d == 0) ? r0 : (d == 1) ? r1 : r2;
    const int*   cc = (d == 0) ? c0 : (d == 1) ? c1 : c2;
    const float* vv = (d == 0) ? v0 : (d == 1) ? v1 : v2;

    __shared__ int   hist[NB_];
    __shared__ int   cur[NB_];
    __shared__ int   base[NB_];
    __shared__ int   gbase[NB_];
    __shared__ uint2 buf[CH_];           // 32 KB

    for (int i = tid; i < NB_; i += 256) { hist[i] = 0; cur[i] = 0; }
    __syncthreads();

    int rloc[16];
#pragma unroll
    for (int j = 0; j < 16; ++j) {
        int e = e0 + j * 256 + tid;
        int r = (e < NNZ_) ? rr[(size_t)b * NNZ_ + e] : -1;
        rloc[j] = r;
        if (r >= 0) atomicAdd(&hist[r >> 7], 1);
    }
    __syncthreads();

    if (tid < 64) {
        int q0 = tid * 7;
        int loc[7];
        int s = 0;
#pragma unroll
        for (int j = 0; j < 7; ++j) {
            int q = q0 + j;
            int h = (q < NB_) ? hist[q] : 0;
            loc[j] = s; s += h;
        }
        int inc = s;
        for (int off = 1; off < 64; off <<= 1) {
            int t = __shfl_up(inc, off, 64);
            if (tid >= off) inc += t;
        }
        int excl = inc - s;
#pragma unroll
        for (int j = 0; j < 7; ++j) {
            int q = q0 + j;
            if (q < NB_) base[q] = excl + loc[j];
        }
    }
    __syncthreads();

#pragma unroll
    for (int j = 0; j < 16; ++j) {
        int r = rloc[j];
        if (r < 0) continue;
        int e = e0 + j * 256 + tid;
        int q = r >> 7;
        int off = atomicAdd(&cur[q], 1);
        int pos = base[q] + off;
        uint2 ent;
        ent.x = __float_as_uint(vv[(size_t)b * NNZ_ + e]);
        ent.y = ((unsigned)q << 23) | ((unsigned)(r & 127) << 16)
              | (unsigned)cc[(size_t)b * NNZ_ + e];
        buf[pos] = ent;
    }
    __syncthreads();

    for (int q = tid; q < NB_; q += 256) {
        int c = cur[q];
        if (c > 0) gbase[q] = atomicAdd(&gcnt[d * NB_ + q], c);
    }
    __syncthreads();

    const int tot = min(CH_, NNZ_ - e0);
#pragma unroll
    for (int j = 0; j < 16; ++j) {
        int i = tid + j * 256;
        if (i >= tot) break;
        uint2 ent = buf[i];
        int q   = ent.y >> 23;
        int dst = gbase[q] + (i - base[q]);
        if (dst < CAP_)
            chunk[(size_t)(d * NB_ + q) * CAP_ + dst] =
                make_uint2(ent.x, ent.y & 0x7fffffu);   // keep rlow|col
    }
}

// ============================================================================
// k_sortgather: fused per-bucket CSR sort (in LDS) + row gather.
// NOW 512 threads (8 waves): same LDS, 4 blocks/CU -> 32 waves/CU (100% occ)
// to hide the L3 gather latency. Sort logic unchanged; gather rl = w, w+8,...
// ============================================================================
__global__ __launch_bounds__(512) void k_sortgather(
    const uint2* __restrict__ chunk, const int* __restrict__ gcnt,
    const us* __restrict__ fb, us* __restrict__ vf)
{
    const int q   = blockIdx.x;
    const int d   = blockIdx.y;
    const int tid = threadIdx.x;
    const int cnt = min(gcnt[d * NB_ + q], CAP_);
    const uint2* cb = chunk + (size_t)(d * NB_ + q) * CAP_;

    __shared__ int   hist[129];
    __shared__ int   lcur[128];
    __shared__ uint2 obuf[CAP_];                // 20 KB

    for (int i = tid; i < 128; i += 512) { hist[i] = 0; lcur[i] = 0; }
    __syncthreads();

    uint2 ent[5];                               // CAP_/512 = 5
    int n = 0;
    for (int i = tid; i < cnt; i += 512) {
        ent[n] = cb[i];
        atomicAdd(&hist[(ent[n].y >> 16) & 127], 1);
        ++n;
    }
    __syncthreads();

    if (tid < 64) {                             // exclusive scan over 128 bins
        int a0 = hist[tid * 2], a1 = hist[tid * 2 + 1];
        int s = a0 + a1;
        int inc = s;
        for (int off = 1; off < 64; off <<= 1) {
            int t = __shfl_up(inc, off, 64);
            if (tid >= off) inc += t;
        }
        int excl = inc - s;
        hist[tid * 2]     = excl;
        hist[tid * 2 + 1] = excl + a0;
        if (tid == 63) hist[128] = inc;         // total
    }
    __syncthreads();

    for (int j = 0; j < n; ++j) {               // permute into row order
        int rl  = (ent[j].y >> 16) & 127;
        int dst = hist[rl] + atomicAdd(&lcur[rl], 1);
        obuf[dst] = make_uint2(ent[j].x, ent[j].y & 0xffffu);   // col only
    }
    __syncthreads();

    // ---- gather phase: wave w handles rows rl = w, w+8, ... ----
    const int w    = tid >> 6;                  // 0..7
    const int lane = tid & 63;
    const int lo2  = lane * 2;
    for (int rl = w; rl < 128; rl += 8) {
        int r = q * 128 + rl;
        if (r >= V_) break;
        int beg = hist[rl], end = hist[rl + 1];

        float ax[8], ay[8];
#pragma unroll
        for (int j = 0; j < 8; ++j) { ax[j] = 0.f; ay[j] = 0.f; }

        int i = beg;
        for (; i + 8 <= end; i += 8) {
            uint2 e[8];
#pragma unroll
            for (int j = 0; j < 8; ++j) e[j] = obuf[i + j];
            unsigned u[8];
#pragma unroll
            for (int j = 0; j < 8; ++j)
                u[j] = *(const unsigned*)&fb[(size_t)e[j].y * 384 + 128 + lo2];
#pragma unroll
            for (int j = 0; j < 8; ++j) {
                float v = __uint_as_float(e[j].x);
                ax[j] += v * b2f((us)(u[j] & 0xffffu));
                ay[j] += v * b2f((us)(u[j] >> 16));
            }
        }
        for (; i < end; ++i) {
            uint2 e0 = obuf[i];
            unsigned u0 = *(const unsigned*)&fb[(size_t)e0.y * 384 + 128 + lo2];
            float v = __uint_as_float(e0.x);
            ax[0] += v * b2f((us)(u0 & 0xffffu));
            ay[0] += v * b2f((us)(u0 >> 16));
        }
        float sx = ((ax[0] + ax[1]) + (ax[2] + ax[3])) + ((ax[4] + ax[5]) + (ax[6] + ax[7]));
        float sy = ((ay[0] + ay[1]) + (ay[2] + ay[3])) + ((ay[4] + ay[5]) + (ay[6] + ay[7]));
        *(unsigned*)&vf[(size_t)r * 384 + d * 128 + lo2] = pk(sx, sy);
    }
}

// ============================================================================
// k_gf_mfma: Av' = vf @ Awb^T (MFMA bf16), then
// f[v][256+c] = bf16(tanh(sum_d Av'[v][d*128+c] * vf[v][d*128+c]))   (r10 proven)
// ============================================================================
__global__ __launch_bounds__(256) void k_gf_mfma(
    const us* __restrict__ vf, const us* __restrict__ Awb,
    us* __restrict__ fb)
{
    const int v0  = blockIdx.x * 64;
    const int tid = threadIdx.x;
    const int w   = tid >> 6;
    const int lr  = tid & 15;
    const int lk  = (tid & 63) >> 4;

    f32x4 z = {0.f, 0.f, 0.f, 0.f};
    f32x4 acc[4][3][2];
#pragma unroll
    for (int mi = 0; mi < 4; ++mi)
#pragma unroll
        for (int d = 0; d < 3; ++d)
#pragma unroll
            for (int ci = 0; ci < 2; ++ci) acc[mi][d][ci] = z;

    const us* aa = vf  + (size_t)(v0 + lr) * 384 + lk * 8;
    const us* bb = Awb + (size_t)(w * 32 + lr) * 384 + lk * 8;
#pragma unroll 2
    for (int kc = 0; kc < 12; ++kc) {
        short8 a[4];
#pragma unroll
        for (int mi = 0; mi < 4; ++mi)
            a[mi] = *(const short8*)(aa + mi * (16 * 384) + kc * 32);
        short8 bm[3][2];
#pragma unroll
        for (int d = 0; d < 3; ++d)
#pragma unroll
            for (int ci = 0; ci < 2; ++ci)
                bm[d][ci] = *(const short8*)(bb + (size_t)(d * 128 + ci * 16) * 384 + kc * 32);
#pragma unroll
        for (int mi = 0; mi < 4; ++mi)
#pragma unroll
            for (int d = 0; d < 3; ++d)
#pragma unroll
                for (int ci = 0; ci < 2; ++ci)
                    acc[mi][d][ci] = __builtin_amdgcn_mfma_f32_16x16x32_bf16(
                        a[mi], bm[d][ci], acc[mi][d][ci], 0, 0, 0);
    }
#pragma unroll
    for (int mi = 0; mi < 4; ++mi)
#pragma unroll
        for (int r = 0; r < 4; ++r) {
            int m = mi * 16 + lk * 4 + r;
            int v = v0 + m;
            if (v < V_) {
#pragma unroll
                for (int ci = 0; ci < 2; ++ci) {
                    int c = w * 32 + ci * 16 + lr;
                    float s = 0.f;
#pragma unroll
                    for (int d = 0; d < 3; ++d)
                        s += acc[mi][d][ci][r] * b2f(vf[(size_t)v * 384 + d * 128 + c]);
                    fb[(size_t)v * 384 + 256 + c] = f2b(tanhf(s));
                }
            }
        }
}

// ============================================================================
// k_mlp_mfma: h = relu(f @ W0^T + b0) (bf16, LDS); out = h @ W1^T + b1 + res
// residual read from fb[v][0:128] (bf16 x_in, L2-hot from GEMM1 A-frags).
// ============================================================================
__global__ __launch_bounds__(256) void k_mlp_mfma(
    const us* __restrict__ fb,
    const us* __restrict__ W0b, const float* __restrict__ b0,
    const us* __restrict__ W1b, const float* __restrict__ b1,
    float* __restrict__ out, int b)
{
    const int v0  = blockIdx.x * 64;
    const int tid = threadIdx.x;
    const int w   = tid >> 6;
    const int lr  = tid & 15;
    const int lk  = (tid & 63) >> 4;

    __shared__ us Hs[64][264];

    f32x4 z = {0.f, 0.f, 0.f, 0.f};
    f32x4 acc[4][4];
#pragma unroll
    for (int mi = 0; mi < 4; ++mi)
#pragma unroll
        for (int ni = 0; ni < 4; ++ni) acc[mi][ni] = z;

    const us* fa = fb  + (size_t)(v0 + lr) * 384 + lk * 8;
    const us* wb = W0b + (size_t)(w * 64 + lr) * 384 + lk * 8;
#pragma unroll 4
    for (int kc = 0; kc < 12; ++kc) {
        short8 a[4], bbf[4];
#pragma unroll
        for (int mi = 0; mi < 4; ++mi)
            a[mi] = *(const short8*)(fa + mi * (16 * 384) + kc * 32);
#pragma unroll
        for (int ni = 0; ni < 4; ++ni)
            bbf[ni] = *(const short8*)(wb + ni * (16 * 384) + kc * 32);
#pragma unroll
        for (int mi = 0; mi < 4; ++mi)
#pragma unroll
            for (int ni = 0; ni < 4; ++ni)
                acc[mi][ni] = __builtin_amdgcn_mfma_f32_16x16x32_bf16(
                    a[mi], bbf[ni], acc[mi][ni], 0, 0, 0);
    }
#pragma unroll
    for (int ni = 0; ni < 4; ++ni) {
        int n = w * 64 + ni * 16 + lr;
        float bias = b0[n];
#pragma unroll
        for (int mi = 0; mi < 4; ++mi)
#pragma unroll
            for (int r = 0; r < 4; ++r) {
                int m = mi * 16 + lk * 4 + r;
                Hs[m][n] = f2b(fmaxf(acc[mi][ni][r] + bias, 0.f));
            }
    }
    __syncthreads();

    f32x4 acc2[4][2];
#pragma unroll
    for (int mi = 0; mi < 4; ++mi)
#pragma unroll
        for (int ni = 0; ni < 2; ++ni) acc2[mi][ni] = z;

    const us* w1b = W1b + (size_t)(w * 32 + lr) * 256 + lk * 8;
#pragma unroll 4
    for (int kc = 0; kc < 8; ++kc) {
        short8 a2[4], b2[2];
#pragma unroll
        for (int mi = 0; mi < 4; ++mi)
            a2[mi] = *(const short8*)&Hs[mi * 16 + lr][kc * 32 + lk * 8];
#pragma unroll
        for (int ni = 0; ni < 2; ++ni)
            b2[ni] = *(const short8*)(w1b + ni * (16 * 256) + kc * 32);
#pragma unroll
        for (int mi = 0; mi < 4; ++mi)
#pragma unroll
            for (int ni = 0; ni < 2; ++ni)
                acc2[mi][ni] = __builtin_amdgcn_mfma_f32_16x16x32_bf16(
                    a2[mi], b2[ni], acc2[mi][ni], 0, 0, 0);
    }
#pragma unroll
    for (int ni = 0; ni < 2; ++ni) {
        int n = w * 32 + ni * 16 + lr;
        float bias = b1[n];
#pragma unroll
        for (int mi = 0; mi < 4; ++mi)
#pragma unroll
            for (int r = 0; r < 4; ++r) {
                int m = mi * 16 + lk * 4 + r;
                int v = v0 + m;
                if (v < V_) {
                    float xi = b2f(fb[(size_t)v * 384 + n]);
                    out[((size_t)b * V_ + v) * C_ + n] = acc2[mi][ni][r] + bias + xi;
                }
            }
    }
}

// ============================================================================
extern "C" void kernel_launch(void* const* d_in, const int* in_sizes, int n_in,
                              void* d_out, int out_size, void* d_ws, size_t ws_size,
                              hipStream_t stream)
{
    const float* x_in  = (const float*)d_in[0];
    const float* evals = (const float*)d_in[1];
    const float* evecs = (const float*)d_in[2];
    const float* mass  = (const float*)d_in[3];
    const float* gv[3] = {(const float*)d_in[4], (const float*)d_in[7], (const float*)d_in[10]};
    const int*   gr[3] = {(const int*)d_in[5],   (const int*)d_in[8],   (const int*)d_in[11]};
    const int*   gc[3] = {(const int*)d_in[6],   (const int*)d_in[9],   (const int*)d_in[12]};
    const float* dt  = (const float*)d_in[13];
    const float* Aw  = (const float*)d_in[14];
    const float* W0  = (const float*)d_in[15];
    const float* b0  = (const float*)d_in[16];
    const float* W1  = (const float*)d_in[17];
    const float* b1  = (const float*)d_in[18];
    float* out = (float*)d_out;

    // ---- workspace layout (chunk & evb time-share the scratch region) ----
    float* x_spec = (float*)d_ws;                            // 65536 f32
    us* spec_t = (us*)(x_spec + 65536);                      // 16384
    us* W0b    = spec_t + 16384;                             // 98304
    us* W1b    = W0b + 98304;                                // 32768
    us* Awb    = W1b + 32768;                                // 147456
    us* fb     = Awb + 147456;                               // VP_*384
    us* vf     = fb + (size_t)VP_ * 384;                     // VP_*384
    us* scratch = vf + (size_t)VP_ * 384;                    // 2*128*VPT_ region
    int* gcnt  = (int*)(scratch + (size_t)256 * VPT_);       // 3*NB_
    // evb (12.85 MB, used specf->frombasis) and chunk (24 MB, binfill->
    // sortgather) alias the same scratch; their live ranges are disjoint.
    us*    evb   = scratch;
    uint2* chunk = (uint2*)scratch;

    hipMemsetAsync(x_spec, 0, 65536 * sizeof(float), stream);
    k_cvt_all<<<dim3(640), 256, 0, stream>>>(W0, W1, Aw, W0b, W1b, Awb);

    for (int b = 0; b < B_; ++b) {
        k_specf<<<dim3(392), 256, 0, stream>>>(x_in, mass, evecs, x_spec, fb, evb, b);
        k_scale2<<<dim3(64), 256, 0, stream>>>(evals, dt, x_spec, spec_t, b);
        k_frombasis_mfma<<<dim3(782), 256, 0, stream>>>(evb, spec_t, fb, b);
        hipMemsetAsync(gcnt, 0, 3 * NB_ * sizeof(int), stream);
        k_binfill<<<dim3(NBF_, 3), 256, 0, stream>>>(
            gr[0], gr[1], gr[2], gc[0], gc[1], gc[2], gv[0], gv[1], gv[2],
            chunk, gcnt, b);
        k_sortgather<<<dim3(NB_, 3), 512, 0, stream>>>(chunk, gcnt, fb, vf);
        k_gf_mfma<<<dim3(782), 256, 0, stream>>>(vf, Awb, fb);
        k_mlp_mfma<<<dim3(782), 256, 0, stream>>>(fb, W0b, b0, W1b, b1, out, b);
    }
}

// Round 19
// 1326.603 us; speedup vs baseline: 1.0207x; 1.0207x over previous
//
#include <hip/hip_runtime.h>
#include <cstdint>
#include <cstddef>

#define B_   4
#define V_   50000
#define VP_  50048                       // 782*64  (fb/vf row count)
#define VPT_ 50176                       // 392*128 (specf grid coverage; evb rows)
#define K_   128
#define C_   128
#define NNZ_ 800000
#define HID_ 256

#define NB_   391                        // buckets of 128 rows
#define CAP_  2560                       // per-(d,bucket) capacity
#define CH_   4096                       // entries per binfill block
#define NBF_  196                        // ceil(NNZ_/CH_)

typedef __attribute__((ext_vector_type(8))) short short8;
typedef __attribute__((ext_vector_type(4))) float f32x4;
typedef unsigned short us;

__device__ __forceinline__ us f2b(float f) {
    union { float f; unsigned u; } v; v.f = f;
    unsigned r = v.u + 0x7fffu + ((v.u >> 16) & 1u);
    return (us)(r >> 16);
}
__device__ __forceinline__ float b2f(us h) {
    union { unsigned u; float f; } v; v.u = ((unsigned)h) << 16; return v.f;
}
__device__ __forceinline__ unsigned pk(float lo, float hi) {
    return (unsigned)f2b(lo) | ((unsigned)f2b(hi) << 16);
}

// ============================================================================
// k_cvt_all: W0/W1 bf16 convert + Aw permuted bf16 convert (one dispatch)
// ============================================================================
__global__ __launch_bounds__(256) void k_cvt_all(
    const float* __restrict__ W0, const float* __restrict__ W1,
    const float* __restrict__ Aw,
    us* __restrict__ W0b, us* __restrict__ W1b, us* __restrict__ Awb)
{
    int t = blockIdx.x * 256 + threadIdx.x;          // 163840 threads total
    if (t < 16384) {
        const float* src; us* dst; int i8;
        if (t < 12288) { i8 = t * 8;            src = W0 + i8; dst = W0b + i8; }
        else           { i8 = (t - 12288) * 8;  src = W1 + i8; dst = W1b + i8; }
        float4 x0 = *(const float4*)src;
        float4 x1 = *(const float4*)(src + 4);
        uint4 u;
        u.x = pk(x0.x, x0.y); u.y = pk(x0.z, x0.w);
        u.z = pk(x1.x, x1.y); u.w = pk(x1.z, x1.w);
        *(uint4*)dst = u;
    } else {
        int p  = t - 16384;                          // < 147456
        int p1 = p / 384, p2 = p - p1 * 384;
        int q1 = 3 * (p1 & 127) + (p1 >> 7);
        int q2 = 3 * (p2 & 127) + (p2 >> 7);
        Awb[p] = f2b(Aw[q1 * 384 + q2]);
    }
}

// ============================================================================
// k_specf: FUSED transpose + spectral projection + evb stash (r17 proven)
// ============================================================================
__global__ __launch_bounds__(256) void k_specf(
    const float* __restrict__ x_in, const float* __restrict__ mass,
    const float* __restrict__ evecs,
    float* __restrict__ x_spec, us* __restrict__ fb, us* __restrict__ evb, int b)
{
    const int vb  = blockIdx.x * 128;
    const int tid = threadIdx.x;
    const int w   = tid >> 6;
    const int lr  = tid & 15;
    const int lk  = (tid & 63) >> 4;

    __shared__ us ev_t[128][40];   // [k][v_local], 80B row stride (16B aligned)
    __shared__ us mx_t[128][40];   // [c][v_local]

    f32x4 z = {0.f, 0.f, 0.f, 0.f};
    f32x4 acc[2][8];
#pragma unroll
    for (int mi = 0; mi < 2; ++mi)
#pragma unroll
        for (int ni = 0; ni < 8; ++ni) acc[mi][ni] = z;

    for (int s = 0; s < 4; ++s) {
        int v0 = vb + s * 32;
        __syncthreads();
#pragma unroll
        for (int it = 0; it < 4; ++it) {
            int f   = tid + it * 256;          // 0..1023
            int row = f >> 5;                  // 0..31
            int col = (f & 31) * 4;
            int v   = v0 + row;
            float4 x = make_float4(0.f, 0.f, 0.f, 0.f);
            float4 e = make_float4(0.f, 0.f, 0.f, 0.f);
            float  m = 0.f;
            if (v < V_) {
                x = *(const float4*)&x_in [((size_t)b * V_ + v) * C_ + col];
                e = *(const float4*)&evecs[((size_t)b * V_ + v) * K_ + col];
                m = mass[b * V_ + v];
                uint2 u; u.x = pk(x.x, x.y); u.y = pk(x.z, x.w);
                *(uint2*)&fb[(size_t)v * 384 + col] = u;
            }
            {   // evb row (unconditional: v < VPT_ always; zeros beyond V_)
                uint2 ue; ue.x = pk(e.x, e.y); ue.y = pk(e.z, e.w);
                *(uint2*)&evb[(size_t)v * 128 + col] = ue;
            }
            mx_t[col + 0][row] = f2b(x.x * m); mx_t[col + 1][row] = f2b(x.y * m);
            mx_t[col + 2][row] = f2b(x.z * m); mx_t[col + 3][row] = f2b(x.w * m);
            ev_t[col + 0][row] = f2b(e.x); ev_t[col + 1][row] = f2b(e.y);
            ev_t[col + 2][row] = f2b(e.z); ev_t[col + 3][row] = f2b(e.w);
        }
        __syncthreads();

        short8 a[2], bf8[8];
#pragma unroll
        for (int mi = 0; mi < 2; ++mi)
            a[mi] = *(const short8*)&ev_t[w * 32 + mi * 16 + lr][lk * 8];
#pragma unroll
        for (int ni = 0; ni < 8; ++ni)
            bf8[ni] = *(const short8*)&mx_t[ni * 16 + lr][lk * 8];
#pragma unroll
        for (int mi = 0; mi < 2; ++mi)
#pragma unroll
            for (int ni = 0; ni < 8; ++ni)
                acc[mi][ni] = __builtin_amdgcn_mfma_f32_16x16x32_bf16(
                    a[mi], bf8[ni], acc[mi][ni], 0, 0, 0);
    }
#pragma unroll
    for (int mi = 0; mi < 2; ++mi)
#pragma unroll
        for (int ni = 0; ni < 8; ++ni)
#pragma unroll
            for (int r = 0; r < 4; ++r) {
                int k = w * 32 + mi * 16 + lk * 4 + r;
                int c = ni * 16 + lr;
                atomicAdd(&x_spec[((size_t)b * K_ + k) * C_ + c], acc[mi][ni][r]);
            }
}

// ============================================================================
// k_scale2: spec_t[c][k] = bf16( exp(-evals[b,k]*max(dt[c],1e-8)) * x_spec[b,k,c] )
// ============================================================================
__global__ __launch_bounds__(256) void k_scale2(
    const float* __restrict__ evals, const float* __restrict__ dt,
    const float* __restrict__ x_spec, us* __restrict__ spec_t, int b)
{
    int i = blockIdx.x * 256 + threadIdx.x;    // < 16384
    int c = i >> 7;
    int k = i & 127;
    float t = fmaxf(dt[c], 1e-8f);
    float v = __expf(-evals[b * K_ + k] * t) * x_spec[((size_t)b * K_ + k) * C_ + c];
    spec_t[i] = f2b(v);
}

// ============================================================================
// k_frombasis_mfma: fb[v][128+c] = bf16( sum_k evb[v][k] * spec_t[c][k] )
// ============================================================================
__global__ __launch_bounds__(256) void k_frombasis_mfma(
    const us* __restrict__ evb, const us* __restrict__ spec_t,
    us* __restrict__ fb, int b)
{
    const int v0  = blockIdx.x * 64;
    const int tid = threadIdx.x;
    const int w   = tid >> 6;
    const int lr  = tid & 15;
    const int lk  = (tid & 63) >> 4;

    f32x4 z = {0.f, 0.f, 0.f, 0.f};
    f32x4 acc[4][2];
#pragma unroll
    for (int mi = 0; mi < 4; ++mi)
#pragma unroll
        for (int ni = 0; ni < 2; ++ni) acc[mi][ni] = z;

#pragma unroll
    for (int ks = 0; ks < 4; ++ks) {
        int ko = ks * 32 + lk * 8;
        short8 a[4], bf[2];
#pragma unroll
        for (int mi = 0; mi < 4; ++mi)
            a[mi] = *(const short8*)&evb[(size_t)(v0 + mi * 16 + lr) * 128 + ko];
#pragma unroll
        for (int ni = 0; ni < 2; ++ni)
            bf[ni] = *(const short8*)&spec_t[(size_t)(w * 32 + ni * 16 + lr) * K_ + ko];
#pragma unroll
        for (int mi = 0; mi < 4; ++mi)
#pragma unroll
            for (int ni = 0; ni < 2; ++ni)
                acc[mi][ni] = __builtin_amdgcn_mfma_f32_16x16x32_bf16(
                    a[mi], bf[ni], acc[mi][ni], 0, 0, 0);
    }
#pragma unroll
    for (int mi = 0; mi < 4; ++mi)
#pragma unroll
        for (int ni = 0; ni < 2; ++ni)
#pragma unroll
            for (int r = 0; r < 4; ++r) {
                int v = v0 + mi * 16 + lk * 4 + r;
                int c = w * 32 + ni * 16 + lr;
                if (v < V_) fb[(size_t)v * 384 + 128 + c] = f2b(acc[mi][ni][r]);
            }
}

// ============================================================================
// k_binfill: LDS-binned bucket scatter (proven). Entry: {val, (q<<23)|(rlow<<16)|col}
// ============================================================================
__global__ __launch_bounds__(256) void k_binfill(
    const int* __restrict__ r0, const int* __restrict__ r1, const int* __restrict__ r2,
    const int* __restrict__ c0, const int* __restrict__ c1, const int* __restrict__ c2,
    const float* __restrict__ v0, const float* __restrict__ v1, const float* __restrict__ v2,
    uint2* __restrict__ chunk, int* __restrict__ gcnt, int b)
{
    const int d   = blockIdx.y;
    const int e0  = blockIdx.x * CH_;
    const int tid = threadIdx.x;
    const int*   rr = (d == 0) ? r0 : (d == 1) ? r1 : r2;
    const int*   cc = (d == 0) ? c0 : (d == 1) ? c1 : c2;
    const float* vv = (d == 0) ? v0 : (d == 1) ? v1 : v2;

    __shared__ int   hist[NB_];
    __shared__ int   cur[NB_];
    __shared__ int   base[NB_];
    __shared__ int   gbase[NB_];
    __shared__ uint2 buf[CH_];           // 32 KB

    for (int i = tid; i < NB_; i += 256) { hist[i] = 0; cur[i] = 0; }
    __syncthreads();

    int rloc[16];
#pragma unroll
    for (int j = 0; j < 16; ++j) {
        int e = e0 + j * 256 + tid;
        int r = (e < NNZ_) ? rr[(size_t)b * NNZ_ + e] : -1;
        rloc[j] = r;
        if (r >= 0) atomicAdd(&hist[r >> 7], 1);
    }
    __syncthreads();

    if (tid < 64) {
        int q0 = tid * 7;
        int loc[7];
        int s = 0;
#pragma unroll
        for (int j = 0; j < 7; ++j) {
            int q = q0 + j;
            int h = (q < NB_) ? hist[q] : 0;
            loc[j] = s; s += h;
        }
        int inc = s;
        for (int off = 1; off < 64; off <<= 1) {
            int t = __shfl_up(inc, off, 64);
            if (tid >= off) inc += t;
        }
        int excl = inc - s;
#pragma unroll
        for (int j = 0; j < 7; ++j) {
            int q = q0 + j;
            if (q < NB_) base[q] = excl + loc[j];
        }
    }
    __syncthreads();

#pragma unroll
    for (int j = 0; j < 16; ++j) {
        int r = rloc[j];
        if (r < 0) continue;
        int e = e0 + j * 256 + tid;
        int q = r >> 7;
        int off = atomicAdd(&cur[q], 1);
        int pos = base[q] + off;
        uint2 ent;
        ent.x = __float_as_uint(vv[(size_t)b * NNZ_ + e]);
        ent.y = ((unsigned)q << 23) | ((unsigned)(r & 127) << 16)
              | (unsigned)cc[(size_t)b * NNZ_ + e];
        buf[pos] = ent;
    }
    __syncthreads();

    for (int q = tid; q < NB_; q += 256) {
        int c = cur[q];
        if (c > 0) gbase[q] = atomicAdd(&gcnt[d * NB_ + q], c);
    }
    __syncthreads();

    const int tot = min(CH_, NNZ_ - e0);
#pragma unroll
    for (int j = 0; j < 16; ++j) {
        int i = tid + j * 256;
        if (i >= tot) break;
        uint2 ent = buf[i];
        int q   = ent.y >> 23;
        int dst = gbase[q] + (i - base[q]);
        if (dst < CAP_)
            chunk[(size_t)(d * NB_ + q) * CAP_ + dst] =
                make_uint2(ent.x, ent.y & 0x7fffffu);   // keep rlow|col
    }
}

// ============================================================================
// k_sortgather: fused per-bucket CSR sort (in LDS) + row gather (r17 proven,
// 256 threads, 1 row per wave, 2 channels/lane, 8-deep unroll).
// ============================================================================
__global__ __launch_bounds__(256) void k_sortgather(
    const uint2* __restrict__ chunk, const int* __restrict__ gcnt,
    const us* __restrict__ fb, us* __restrict__ vf)
{
    const int q   = blockIdx.x;
    const int d   = blockIdx.y;
    const int tid = threadIdx.x;
    const int cnt = min(gcnt[d * NB_ + q], CAP_);
    const uint2* cb = chunk + (size_t)(d * NB_ + q) * CAP_;

    __shared__ int   hist[129];
    __shared__ int   lcur[128];
    __shared__ uint2 obuf[CAP_];                // 20 KB

    for (int i = tid; i < 128; i += 256) { hist[i] = 0; lcur[i] = 0; }
    __syncthreads();

    uint2 ent[10];                              // CAP_/256 = 10
    int n = 0;
    for (int i = tid; i < cnt; i += 256) {
        ent[n] = cb[i];
        atomicAdd(&hist[(ent[n].y >> 16) & 127], 1);
        ++n;
    }
    __syncthreads();

    if (tid < 64) {                             // exclusive scan over 128 bins
        int a0 = hist[tid * 2], a1 = hist[tid * 2 + 1];
        int s = a0 + a1;
        int inc = s;
        for (int off = 1; off < 64; off <<= 1) {
            int t = __shfl_up(inc, off, 64);
            if (tid >= off) inc += t;
        }
        int excl = inc - s;
        hist[tid * 2]     = excl;
        hist[tid * 2 + 1] = excl + a0;
        if (tid == 63) hist[128] = inc;         // total
    }
    __syncthreads();

    for (int j = 0; j < n; ++j) {               // permute into row order
        int rl  = (ent[j].y >> 16) & 127;
        int dst = hist[rl] + atomicAdd(&lcur[rl], 1);
        obuf[dst] = make_uint2(ent[j].x, ent[j].y & 0xffffu);   // col only
    }
    __syncthreads();

    // ---- gather phase: wave w handles rows rl = w, w+4, ... ----
    const int w    = tid >> 6;
    const int lane = tid & 63;
    const int lo2  = lane * 2;
    for (int rl = w; rl < 128; rl += 4) {
        int r = q * 128 + rl;
        if (r >= V_) break;
        int beg = hist[rl], end = hist[rl + 1];

        float ax[8], ay[8];
#pragma unroll
        for (int j = 0; j < 8; ++j) { ax[j] = 0.f; ay[j] = 0.f; }

        int i = beg;
        for (; i + 8 <= end; i += 8) {
            uint2 e[8];
#pragma unroll
            for (int j = 0; j < 8; ++j) e[j] = obuf[i + j];
            unsigned u[8];
#pragma unroll
            for (int j = 0; j < 8; ++j)
                u[j] = *(const unsigned*)&fb[(size_t)e[j].y * 384 + 128 + lo2];
#pragma unroll
            for (int j = 0; j < 8; ++j) {
                float v = __uint_as_float(e[j].x);
                ax[j] += v * b2f((us)(u[j] & 0xffffu));
                ay[j] += v * b2f((us)(u[j] >> 16));
            }
        }
        for (; i < end; ++i) {
            uint2 e0 = obuf[i];
            unsigned u0 = *(const unsigned*)&fb[(size_t)e0.y * 384 + 128 + lo2];
            float v = __uint_as_float(e0.x);
            ax[0] += v * b2f((us)(u0 & 0xffffu));
            ay[0] += v * b2f((us)(u0 >> 16));
        }
        float sx = ((ax[0] + ax[1]) + (ax[2] + ax[3])) + ((ax[4] + ax[5]) + (ax[6] + ax[7]));
        float sy = ((ay[0] + ay[1]) + (ay[2] + ay[3])) + ((ay[4] + ay[5]) + (ay[6] + ay[7]));
        *(unsigned*)&vf[(size_t)r * 384 + d * 128 + lo2] = pk(sx, sy);
    }
}

// ============================================================================
// k_gf_mfma: Av' = vf @ Awb^T (MFMA bf16), then
// f[v][256+c] = bf16(tanh(sum_d Av'[v][d*128+c] * vf[v][d*128+c]))   (r10 proven)
// ============================================================================
__global__ __launch_bounds__(256) void k_gf_mfma(
    const us* __restrict__ vf, const us* __restrict__ Awb,
    us* __restrict__ fb)
{
    const int v0  = blockIdx.x * 64;
    const int tid = threadIdx.x;
    const int w   = tid >> 6;
    const int lr  = tid & 15;
    const int lk  = (tid & 63) >> 4;

    f32x4 z = {0.f, 0.f, 0.f, 0.f};
    f32x4 acc[4][3][2];
#pragma unroll
    for (int mi = 0; mi < 4; ++mi)
#pragma unroll
        for (int d = 0; d < 3; ++d)
#pragma unroll
            for (int ci = 0; ci < 2; ++ci) acc[mi][d][ci] = z;

    const us* aa = vf  + (size_t)(v0 + lr) * 384 + lk * 8;
    const us* bb = Awb + (size_t)(w * 32 + lr) * 384 + lk * 8;
#pragma unroll 2
    for (int kc = 0; kc < 12; ++kc) {
        short8 a[4];
#pragma unroll
        for (int mi = 0; mi < 4; ++mi)
            a[mi] = *(const short8*)(aa + mi * (16 * 384) + kc * 32);
        short8 bm[3][2];
#pragma unroll
        for (int d = 0; d < 3; ++d)
#pragma unroll
            for (int ci = 0; ci < 2; ++ci)
                bm[d][ci] = *(const short8*)(bb + (size_t)(d * 128 + ci * 16) * 384 + kc * 32);
#pragma unroll
        for (int mi = 0; mi < 4; ++mi)
#pragma unroll
            for (int d = 0; d < 3; ++d)
#pragma unroll
                for (int ci = 0; ci < 2; ++ci)
                    acc[mi][d][ci] = __builtin_amdgcn_mfma_f32_16x16x32_bf16(
                        a[mi], bm[d][ci], acc[mi][d][ci], 0, 0, 0);
    }
#pragma unroll
    for (int mi = 0; mi < 4; ++mi)
#pragma unroll
        for (int r = 0; r < 4; ++r) {
            int m = mi * 16 + lk * 4 + r;
            int v = v0 + m;
            if (v < V_) {
#pragma unroll
                for (int ci = 0; ci < 2; ++ci) {
                    int c = w * 32 + ci * 16 + lr;
                    float s = 0.f;
#pragma unroll
                    for (int d = 0; d < 3; ++d)
                        s += acc[mi][d][ci][r] * b2f(vf[(size_t)v * 384 + d * 128 + c]);
                    fb[(size_t)v * 384 + 256 + c] = f2b(tanhf(s));
                }
            }
        }
}

// ============================================================================
// k_mlp_mfma: h = relu(f @ W0^T + b0) (bf16, LDS); out = h @ W1^T + b1 + res
// residual read from fb[v][0:128] (bf16 x_in, L2-hot from GEMM1 A-frags).
// ============================================================================
__global__ __launch_bounds__(256) void k_mlp_mfma(
    const us* __restrict__ fb,
    const us* __restrict__ W0b, const float* __restrict__ b0,
    const us* __restrict__ W1b, const float* __restrict__ b1,
    float* __restrict__ out, int b)
{
    const int v0  = blockIdx.x * 64;
    const int tid = threadIdx.x;
    const int w   = tid >> 6;
    const int lr  = tid & 15;
    const int lk  = (tid & 63) >> 4;

    __shared__ us Hs[64][264];

    f32x4 z = {0.f, 0.f, 0.f, 0.f};
    f32x4 acc[4][4];
#pragma unroll
    for (int mi = 0; mi < 4; ++mi)
#pragma unroll
        for (int ni = 0; ni < 4; ++ni) acc[mi][ni] = z;

    const us* fa = fb  + (size_t)(v0 + lr) * 384 + lk * 8;
    const us* wb = W0b + (size_t)(w * 64 + lr) * 384 + lk * 8;
#pragma unroll 4
    for (int kc = 0; kc < 12; ++kc) {
        short8 a[4], bbf[4];
#pragma unroll
        for (int mi = 0; mi < 4; ++mi)
            a[mi] = *(const short8*)(fa + mi * (16 * 384) + kc * 32);
#pragma unroll
        for (int ni = 0; ni < 4; ++ni)
            bbf[ni] = *(const short8*)(wb + ni * (16 * 384) + kc * 32);
#pragma unroll
        for (int mi = 0; mi < 4; ++mi)
#pragma unroll
            for (int ni = 0; ni < 4; ++ni)
                acc[mi][ni] = __builtin_amdgcn_mfma_f32_16x16x32_bf16(
                    a[mi], bbf[ni], acc[mi][ni], 0, 0, 0);
    }
#pragma unroll
    for (int ni = 0; ni < 4; ++ni) {
        int n = w * 64 + ni * 16 + lr;
        float bias = b0[n];
#pragma unroll
        for (int mi = 0; mi < 4; ++mi)
#pragma unroll
            for (int r = 0; r < 4; ++r) {
                int m = mi * 16 + lk * 4 + r;
                Hs[m][n] = f2b(fmaxf(acc[mi][ni][r] + bias, 0.f));
            }
    }
    __syncthreads();

    f32x4 acc2[4][2];
#pragma unroll
    for (int mi = 0; mi < 4; ++mi)
#pragma unroll
        for (int ni = 0; ni < 2; ++ni) acc2[mi][ni] = z;

    const us* w1b = W1b + (size_t)(w * 32 + lr) * 256 + lk * 8;
#pragma unroll 4
    for (int kc = 0; kc < 8; ++kc) {
        short8 a2[4], b2[2];
#pragma unroll
        for (int mi = 0; mi < 4; ++mi)
            a2[mi] = *(const short8*)&Hs[mi * 16 + lr][kc * 32 + lk * 8];
#pragma unroll
        for (int ni = 0; ni < 2; ++ni)
            b2[ni] = *(const short8*)(w1b + ni * (16 * 256) + kc * 32);
#pragma unroll
        for (int mi = 0; mi < 4; ++mi)
#pragma unroll
            for (int ni = 0; ni < 2; ++ni)
                acc2[mi][ni] = __builtin_amdgcn_mfma_f32_16x16x32_bf16(
                    a2[mi], b2[ni], acc2[mi][ni], 0, 0, 0);
    }
#pragma unroll
    for (int ni = 0; ni < 2; ++ni) {
        int n = w * 32 + ni * 16 + lr;
        float bias = b1[n];
#pragma unroll
        for (int mi = 0; mi < 4; ++mi)
#pragma unroll
            for (int r = 0; r < 4; ++r) {
                int m = mi * 16 + lk * 4 + r;
                int v = v0 + m;
                if (v < V_) {
                    float xi = b2f(fb[(size_t)v * 384 + n]);
                    out[((size_t)b * V_ + v) * C_ + n] = acc2[mi][ni][r] + bias + xi;
                }
            }
    }
}

// ============================================================================
extern "C" void kernel_launch(void* const* d_in, const int* in_sizes, int n_in,
                              void* d_out, int out_size, void* d_ws, size_t ws_size,
                              hipStream_t stream)
{
    const float* x_in  = (const float*)d_in[0];
    const float* evals = (const float*)d_in[1];
    const float* evecs = (const float*)d_in[2];
    const float* mass  = (const float*)d_in[3];
    const float* gv[3] = {(const float*)d_in[4], (const float*)d_in[7], (const float*)d_in[10]};
    const int*   gr[3] = {(const int*)d_in[5],   (const int*)d_in[8],   (const int*)d_in[11]};
    const int*   gc[3] = {(const int*)d_in[6],   (const int*)d_in[9],   (const int*)d_in[12]};
    const float* dt  = (const float*)d_in[13];
    const float* Aw  = (const float*)d_in[14];
    const float* W0  = (const float*)d_in[15];
    const float* b0  = (const float*)d_in[16];
    const float* W1  = (const float*)d_in[17];
    const float* b1  = (const float*)d_in[18];
    float* out = (float*)d_out;

    // ---- workspace layout (chunk & evb time-share the scratch region) ----
    float* x_spec = (float*)d_ws;                            // 65536 f32
    us* spec_t = (us*)(x_spec + 65536);                      // 16384
    us* W0b    = spec_t + 16384;                             // 98304
    us* W1b    = W0b + 98304;                                // 32768
    us* Awb    = W1b + 32768;                                // 147456
    us* fb     = Awb + 147456;                               // VP_*384
    us* vf     = fb + (size_t)VP_ * 384;                     // VP_*384
    us* scratch = vf + (size_t)VP_ * 384;                    // 2*128*VPT_ region
    int* gcnt  = (int*)(scratch + (size_t)256 * VPT_);       // 3*NB_
    // evb (12.85 MB, used specf->frombasis) and chunk (24 MB, binfill->
    // sortgather) alias the same scratch; their live ranges are disjoint.
    us*    evb   = scratch;
    uint2* chunk = (uint2*)scratch;

    hipMemsetAsync(x_spec, 0, 65536 * sizeof(float), stream);
    k_cvt_all<<<dim3(640), 256, 0, stream>>>(W0, W1, Aw, W0b, W1b, Awb);

    for (int b = 0; b < B_; ++b) {
        k_specf<<<dim3(392), 256, 0, stream>>>(x_in, mass, evecs, x_spec, fb, evb, b);
        k_scale2<<<dim3(64), 256, 0, stream>>>(evals, dt, x_spec, spec_t, b);
        k_frombasis_mfma<<<dim3(782), 256, 0, stream>>>(evb, spec_t, fb, b);
        hipMemsetAsync(gcnt, 0, 3 * NB_ * sizeof(int), stream);
        k_binfill<<<dim3(NBF_, 3), 256, 0, stream>>>(
            gr[0], gr[1], gr[2], gc[0], gc[1], gc[2], gv[0], gv[1], gv[2],
            chunk, gcnt, b);
        k_sortgather<<<dim3(NB_, 3), 256, 0, stream>>>(chunk, gcnt, fb, vf);
        k_gf_mfma<<<dim3(782), 256, 0, stream>>>(vf, Awb, fb);
        k_mlp_mfma<<<dim3(782), 256, 0, stream>>>(fb, W0b, b0, W1b, b1, out, b);
    }
}